// Round 1
// baseline (1357.891 us; speedup 1.0000x reference)
//
#include <hip/hip_runtime.h>

#define XS 256
#define XS2 65536
#define LAT 10

// ---------------------------------------------------------------------------
// Kernel 1: bilinear point scatter.
// coords: v = (inds[2], inds[1], inds[0]) - 128 + flow;  p_r = sum_c v_c*R[r,c]
// p = p[0:2] - shift + 128;  c_sampling = (p1, p0)
// splat values[n] bilinearly at (row=floor(cs0), col=floor(cs1)).
// JAX .at[].add: negative indices wrap once, then OOB dropped ->
// valid iff i in [-256,256), idx = (i+256)&255.
// ---------------------------------------------------------------------------
__global__ void scatter_kernel(const float* __restrict__ flow,
                               const float* __restrict__ values,
                               const int* __restrict__ inds,
                               const float* __restrict__ rot,
                               const float* __restrict__ shifts,
                               float* __restrict__ img, int N) {
    int b = blockIdx.y;
    int n = blockIdx.x * blockDim.x + threadIdx.x;
    if (n >= N) return;

    const float* R = rot + b * 9;
    float r00 = R[0], r01 = R[1], r02 = R[2];
    float r10 = R[3], r11 = R[4], r12 = R[5];
    float s0 = shifts[b * 2 + 0], s1 = shifts[b * 2 + 1];

    size_t fo = ((size_t)b * N + n) * 3;
    float fw0 = flow[fo + 0], fw1 = flow[fo + 1], fw2 = flow[fo + 2];
    int i0i = inds[n * 3 + 0], i1i = inds[n * 3 + 1], i2i = inds[n * 3 + 2];

    float v0 = (float)i2i - 128.0f + fw0;
    float v1 = (float)i1i - 128.0f + fw1;
    float v2 = (float)i0i - 128.0f + fw2;

    float p0 = v0 * r00 + v1 * r01 + v2 * r02 - s0 + 128.0f;
    float p1 = v0 * r10 + v1 * r11 + v2 * r12 - s1 + 128.0f;

    float cs0 = p1, cs1 = p0;             // c_sampling = (coords[...,1], coords[...,0])
    float ff0 = floorf(cs0), ff1 = floorf(cs1);
    int   r = (int)ff0, c = (int)ff1;
    float f0 = cs0 - ff0, f1 = cs1 - ff1;

    float amp = values[n];
    float a0 = amp * (1.0f - f0) * (1.0f - f1);  // (r,   c)
    float a1 = amp * f0 * (1.0f - f1);           // (r+1, c)
    float a2 = amp * f0 * f1;                    // (r+1, c+1)
    float a3 = amp * (1.0f - f0) * f1;           // (r,   c+1)

    float* I = img + (size_t)b * XS2;
#define SCAT(rr, cc, aa)                                                     \
    do {                                                                     \
        int _r = (rr), _c = (cc);                                            \
        if (_r >= -XS && _r < XS && _c >= -XS && _c < XS) {                  \
            atomicAdd(I + (((_r + XS) & (XS - 1)) * XS +                     \
                           ((_c + XS) & (XS - 1))), (aa));                   \
        }                                                                    \
    } while (0)
    SCAT(r,     c,     a0);
    SCAT(r + 1, c,     a1);
    SCAT(r + 1, c + 1, a2);
    SCAT(r,     c + 1, a3);
#undef SCAT
}

// ---------------------------------------------------------------------------
// Kernel 2: split-K MLP partials. h_raw[b,l] = sum_e x[b,e]*w1[e,l]
// grid = 256 K-chunks of 256 elements; thread t handles (b,l) pair.
// ---------------------------------------------------------------------------
__global__ void mlp_partial(const float* __restrict__ x,
                            const float* __restrict__ w1,
                            float* __restrict__ hraw, int B) {
    int base = blockIdx.x * 256;
    int t = threadIdx.x;
    if (t >= B * LAT) return;
    int b = t / LAT, l = t - b * LAT;
    const float* xb = x + (size_t)b * XS2 + base;
    const float* w  = w1 + (size_t)base * LAT + l;
    float acc = 0.0f;
#pragma unroll 8
    for (int e = 0; e < 256; e++) acc += xb[e] * w[e * LAT];
    atomicAdd(&hraw[b * LAT + l], acc);
}

// ---------------------------------------------------------------------------
// Kernel 3: separable 3x3 blur (zero-pad SAME) + per-batch affine from MLP.
// One block per (b, row); 256 threads = columns.
// ---------------------------------------------------------------------------
__global__ void blur_kernel(const float* __restrict__ img,
                            const float* __restrict__ hraw,
                            const float* __restrict__ b1,
                            const float* __restrict__ w2,
                            const float* __restrict__ b2,
                            float* __restrict__ out) {
    int b = blockIdx.y, r = blockIdx.x, c = threadIdx.x;

    // finalize MLP redundantly (wave-uniform, ~20 scalar FMAs)
    float av = b2[0], bv = b2[1];
#pragma unroll
    for (int l = 0; l < LAT; l++) {
        float h = hraw[b * LAT + l] + b1[l];
        h = h > 0.0f ? h : 0.0f;
        av += h * w2[l * 2 + 0];
        bv += h * w2[l * 2 + 1];
    }

    const float g   = 0.6065306597126334f;     // exp(-0.5)
    const float inv = 1.0f / (1.0f + 2.0f * g);

    const float* I = img + (size_t)b * XS2;
    float up  = (r > 0)      ? I[(r - 1) * XS + c] : 0.0f;
    float mid =                I[r * XS + c];
    float dn  = (r < XS - 1) ? I[(r + 1) * XS + c] : 0.0f;
    float v = (g * (up + dn) + mid) * inv;      // vertical pass

    __shared__ float row[XS + 2];
    row[c + 1] = v;
    if (c == 0) { row[0] = 0.0f; row[XS + 1] = 0.0f; }
    __syncthreads();
    float hh = (g * (row[c] + row[c + 2]) + v) * inv;  // horizontal pass

    out[(size_t)b * XS2 + (size_t)r * XS + c] = av * hh + bv;
}

extern "C" void kernel_launch(void* const* d_in, const int* in_sizes, int n_in,
                              void* d_out, int out_size, void* d_ws, size_t ws_size,
                              hipStream_t stream) {
    const float* flow   = (const float*)d_in[0];
    const float* x      = (const float*)d_in[1];
    const float* values = (const float*)d_in[2];
    const float* rot    = (const float*)d_in[3];
    const float* shifts = (const float*)d_in[4];
    const float* w1     = (const float*)d_in[5];
    const float* b1     = (const float*)d_in[6];
    const float* w2     = (const float*)d_in[7];
    const float* b2     = (const float*)d_in[8];
    const int*   inds   = (const int*)d_in[9];

    int N = in_sizes[2];          // values: (N,)
    int B = in_sizes[4] / 2;      // shifts: (B,2)

    float* img  = (float*)d_ws;                 // B*256*256 f32 accumulator
    float* hraw = img + (size_t)B * XS2;        // B*LAT f32 MLP partials

    hipMemsetAsync(d_ws, 0, ((size_t)B * XS2 + (size_t)B * LAT) * sizeof(float), stream);

    dim3 g1((N + 255) / 256, B);
    scatter_kernel<<<g1, 256, 0, stream>>>(flow, values, inds, rot, shifts, img, N);

    mlp_partial<<<XS2 / 256, 256, 0, stream>>>(x, w1, hraw, B);

    dim3 g3(XS, B);
    blur_kernel<<<g3, XS, 0, stream>>>(img, hraw, b1, w2, b2, (float*)d_out);
}

// Round 2
// 407.237 us; speedup vs baseline: 3.3344x; 3.3344x over previous
//
#include <hip/hip_runtime.h>

#define XS   256
#define XS2  65536
#define LAT  10
#define BR   8            // rows per bin group
#define NG   (XS / BR)    // 32 groups per image
#define P1   1024         // blocks for hist/place passes
#define MAXBINS 512

// ---------------------------------------------------------------------------
// Shared coordinate math — pinned with fmaf so hist_kernel and place_kernel
// produce bit-identical (r,c) and agree on the fast/fallback split.
// ---------------------------------------------------------------------------
__device__ __forceinline__ void compute_rc(const float* __restrict__ flow,
                                           const int* __restrict__ inds,
                                           const float* __restrict__ rot,
                                           const float* __restrict__ shifts,
                                           int b, int n, int N,
                                           int& r, int& c, float& f0, float& f1) {
    const float* R = rot + b * 9;
    float r00 = R[0], r01 = R[1], r02 = R[2];
    float r10 = R[3], r11 = R[4], r12 = R[5];
    float s0 = shifts[b * 2 + 0], s1 = shifts[b * 2 + 1];
    size_t fo = ((size_t)b * N + n) * 3;
    float fw0 = flow[fo + 0], fw1 = flow[fo + 1], fw2 = flow[fo + 2];
    float v0 = (float)inds[n * 3 + 2] - 128.0f + fw0;
    float v1 = (float)inds[n * 3 + 1] - 128.0f + fw1;
    float v2 = (float)inds[n * 3 + 0] - 128.0f + fw2;
    float p0 = fmaf(v0, r00, fmaf(v1, r01, fmaf(v2, r02, 128.0f - s0)));
    float p1 = fmaf(v0, r10, fmaf(v1, r11, fmaf(v2, r12, 128.0f - s1)));
    float cs0 = p1, cs1 = p0;     // c_sampling = (coords[...,1], coords[...,0])
    float ff0 = floorf(cs0), ff1 = floorf(cs1);
    r = (int)ff0; c = (int)ff1;
    f0 = cs0 - ff0; f1 = cs1 - ff1;
}

__device__ __forceinline__ void corner_atomic(float* I, int rr, int cc, float a) {
    if (rr >= -XS && rr < XS && cc >= -XS && cc < XS)
        atomicAdd(I + ((rr + XS) & (XS - 1)) * XS + ((cc + XS) & (XS - 1)), a);
}

// fast path iff rows r and r+1 are both valid and don't wrap-split:
// r in [-256, 254] and r != -1  =>  wrapped rows are wr, wr+1 with wr <= 254.
__device__ __forceinline__ bool is_fast(int r) {
    return (r >= -XS) && (r <= XS - 2) && (r != -1);
}

// ---------------------------------------------------------------------------
// Pass 1: per-block histogram of fast-path splats over (b, rowgroup) bins.
// ---------------------------------------------------------------------------
__global__ void hist_kernel(const float* __restrict__ flow,
                            const int* __restrict__ inds,
                            const float* __restrict__ rot,
                            const float* __restrict__ shifts,
                            unsigned* __restrict__ hist,
                            int N, int TI, int IPB, int NB) {
    __shared__ unsigned lh[MAXBINS];
    int t = threadIdx.x;
    for (int k = t; k < NB; k += 256) lh[k] = 0;
    __syncthreads();
    int s = blockIdx.x * IPB;
    int e = min(s + IPB, TI);
    for (int i = s + t; i < e; i += 256) {
        int b = i / N, n = i - b * N;
        int r, c; float f0, f1;
        compute_rc(flow, inds, rot, shifts, b, n, N, r, c, f0, f1);
        if (is_fast(r)) {
            int wr = (r + XS) & (XS - 1);
            atomicAdd(&lh[b * NG + (wr >> 3)], 1u);
        }
    }
    __syncthreads();
    for (int k = t; k < NB; k += 256) hist[(size_t)k * P1 + blockIdx.x] = lh[k];
}

// ---------------------------------------------------------------------------
// Pass 2a: per-bin totals.
// ---------------------------------------------------------------------------
__global__ void bin_total_kernel(const unsigned* __restrict__ hist,
                                 unsigned* __restrict__ totals) {
    int bin = blockIdx.x, t = threadIdx.x;
    unsigned s = 0;
    for (int p = t; p < P1; p += 256) s += hist[(size_t)bin * P1 + p];
    __shared__ unsigned red[256];
    red[t] = s; __syncthreads();
    for (int st = 128; st > 0; st >>= 1) {
        if (t < st) red[t] += red[t + st];
        __syncthreads();
    }
    if (t == 0) totals[bin] = red[0];
}

// ---------------------------------------------------------------------------
// Pass 2b: exclusive scan of bin totals (one block).
// ---------------------------------------------------------------------------
__global__ void base_scan_kernel(const unsigned* __restrict__ totals,
                                 unsigned* __restrict__ base, int nb) {
    __shared__ unsigned sh[MAXBINS];
    int t = threadIdx.x;
    unsigned v = (t < nb) ? totals[t] : 0u;
    sh[t] = v; __syncthreads();
    for (int st = 1; st < MAXBINS; st <<= 1) {
        unsigned add = (t >= st) ? sh[t - st] : 0u;
        __syncthreads();
        sh[t] += add;
        __syncthreads();
    }
    if (t < nb) base[t] = sh[t] - v;
}

// ---------------------------------------------------------------------------
// Pass 2c: per-bin exclusive scan over the P1 block counts -> placement offs.
// ---------------------------------------------------------------------------
__global__ void offs_scan_kernel(const unsigned* __restrict__ hist,
                                 const unsigned* __restrict__ base,
                                 unsigned* __restrict__ offs) {
    int bin = blockIdx.x, t = threadIdx.x;
    const unsigned* h = hist + (size_t)bin * P1;
    unsigned* o = offs + (size_t)bin * P1;
    unsigned v[4]; unsigned s = 0;
#pragma unroll
    for (int k = 0; k < 4; k++) { v[k] = h[t * 4 + k]; s += v[k]; }
    __shared__ unsigned sh[256];
    sh[t] = s; __syncthreads();
    for (int st = 1; st < 256; st <<= 1) {
        unsigned add = (t >= st) ? sh[t - st] : 0u;
        __syncthreads();
        sh[t] += add;
        __syncthreads();
    }
    unsigned run = base[bin] + sh[t] - s;
#pragma unroll
    for (int k = 0; k < 4; k++) { o[t * 4 + k] = run; run += v[k]; }
}

// ---------------------------------------------------------------------------
// Pass 3: recompute and place splat records (SoA); rare cases direct-atomic.
// record: hdr = wr | wc<<8 | cv0<<16 | cv1<<17 ; frac = q0 | q1<<16 ; amp f32
// ---------------------------------------------------------------------------
__global__ void place_kernel(const float* __restrict__ flow,
                             const float* __restrict__ values,
                             const int* __restrict__ inds,
                             const float* __restrict__ rot,
                             const float* __restrict__ shifts,
                             const unsigned* __restrict__ offs,
                             unsigned* __restrict__ hdr,
                             unsigned* __restrict__ fracs,
                             float* __restrict__ amps,
                             float* __restrict__ img,
                             int N, int TI, int IPB, int NB) {
    __shared__ unsigned cur[MAXBINS];
    int t = threadIdx.x;
    for (int k = t; k < NB; k += 256) cur[k] = offs[(size_t)k * P1 + blockIdx.x];
    __syncthreads();
    int s = blockIdx.x * IPB;
    int e = min(s + IPB, TI);
    for (int i = s + t; i < e; i += 256) {
        int b = i / N, n = i - b * N;
        int r, c; float f0, f1;
        compute_rc(flow, inds, rot, shifts, b, n, N, r, c, f0, f1);
        float amp = values[n];
        if (is_fast(r)) {
            int wr = (r + XS) & (XS - 1);
            int wc = c & (XS - 1);
            unsigned cv0 = (c >= -XS && c < XS) ? 1u : 0u;
            unsigned cv1 = (c + 1 >= -XS && c + 1 < XS) ? 1u : 0u;
            unsigned idx = atomicAdd(&cur[b * NG + (wr >> 3)], 1u);
            hdr[idx]   = (unsigned)wr | ((unsigned)wc << 8) | (cv0 << 16) | (cv1 << 17);
            unsigned q0 = (unsigned)(f0 * 65536.0f);
            unsigned q1 = (unsigned)(f1 * 65536.0f);
            fracs[idx] = q0 | (q1 << 16);
            amps[idx]  = amp;
        } else {
            float a0 = amp * (1.0f - f0) * (1.0f - f1);
            float a1 = amp * f0 * (1.0f - f1);
            float a2 = amp * f0 * f1;
            float a3 = amp * (1.0f - f0) * f1;
            float* I = img + (size_t)b * XS2;
            corner_atomic(I, r,     c,     a0);
            corner_atomic(I, r + 1, c,     a1);
            corner_atomic(I, r + 1, c + 1, a2);
            corner_atomic(I, r,     c + 1, a3);
        }
    }
}

// ---------------------------------------------------------------------------
// Pass 4: per-bin LDS accumulation (9 rows x 256 cols) + coalesced flush.
// ---------------------------------------------------------------------------
__global__ void accum_kernel(const unsigned* __restrict__ hdr,
                             const unsigned* __restrict__ fracs,
                             const float* __restrict__ amps,
                             const unsigned* __restrict__ base,
                             const unsigned* __restrict__ totals,
                             float* __restrict__ img) {
    int bin = blockIdx.x;
    int b = bin / NG, g = bin - b * NG;
    __shared__ float tile[(BR + 1) * XS];
    int t = threadIdx.x;
    for (int k = t; k < (BR + 1) * XS; k += 256) tile[k] = 0.0f;
    __syncthreads();
    unsigned s = base[bin], cnt = totals[bin];
    for (unsigned i = s + t; i < s + cnt; i += 256) {
        unsigned h = hdr[i], q = fracs[i];
        float amp = amps[i];
        int wr = h & 255, wc = (h >> 8) & 255;
        float f0 = (float)(q & 0xffffu) * (1.0f / 65536.0f);
        float f1 = (float)(q >> 16) * (1.0f / 65536.0f);
        int row = wr - g * BR;
        int o0 = row * XS + wc;
        float g0 = 1.0f - f0, g1 = 1.0f - f1;
        if (h & (1u << 16)) {
            atomicAdd(&tile[o0],      amp * g0 * g1);
            atomicAdd(&tile[o0 + XS], amp * f0 * g1);
        }
        if (h & (1u << 17)) {
            int p0 = row * XS + ((wc + 1) & (XS - 1));
            atomicAdd(&tile[p0],      amp * g0 * f1);
            atomicAdd(&tile[p0 + XS], amp * f0 * f1);
        }
    }
    __syncthreads();
    float* I = img + (size_t)b * XS2;
    for (int k = t; k < (BR + 1) * XS; k += 256) {
        float v = tile[k];
        if (v != 0.0f) {
            int rr = (g * BR + (k >> 8)) & (XS - 1);   // apron row 256 wraps to 0 (never hit)
            atomicAdd(&I[rr * XS + (k & 255)], v);
        }
    }
}

// ---------------------------------------------------------------------------
// Fallback direct-scatter (round-1 path) if ws too small.
// ---------------------------------------------------------------------------
__global__ void scatter_kernel(const float* __restrict__ flow,
                               const float* __restrict__ values,
                               const int* __restrict__ inds,
                               const float* __restrict__ rot,
                               const float* __restrict__ shifts,
                               float* __restrict__ img, int N) {
    int b = blockIdx.y;
    int n = blockIdx.x * blockDim.x + threadIdx.x;
    if (n >= N) return;
    int r, c; float f0, f1;
    compute_rc(flow, inds, rot, shifts, b, n, N, r, c, f0, f1);
    float amp = values[n];
    float a0 = amp * (1.0f - f0) * (1.0f - f1);
    float a1 = amp * f0 * (1.0f - f1);
    float a2 = amp * f0 * f1;
    float a3 = amp * (1.0f - f0) * f1;
    float* I = img + (size_t)b * XS2;
    corner_atomic(I, r,     c,     a0);
    corner_atomic(I, r + 1, c,     a1);
    corner_atomic(I, r + 1, c + 1, a2);
    corner_atomic(I, r,     c + 1, a3);
}

// ---------------------------------------------------------------------------
// MLP split-K partials.
// ---------------------------------------------------------------------------
__global__ void mlp_partial(const float* __restrict__ x,
                            const float* __restrict__ w1,
                            float* __restrict__ hraw, int B) {
    int base = blockIdx.x * 256;
    int t = threadIdx.x;
    if (t >= B * LAT) return;
    int b = t / LAT, l = t - b * LAT;
    const float* xb = x + (size_t)b * XS2 + base;
    const float* w  = w1 + (size_t)base * LAT + l;
    float acc = 0.0f;
#pragma unroll 8
    for (int e = 0; e < 256; e++) acc += xb[e] * w[e * LAT];
    atomicAdd(&hraw[b * LAT + l], acc);
}

// ---------------------------------------------------------------------------
// Separable 3x3 blur + per-batch affine.
// ---------------------------------------------------------------------------
__global__ void blur_kernel(const float* __restrict__ img,
                            const float* __restrict__ hraw,
                            const float* __restrict__ b1,
                            const float* __restrict__ w2,
                            const float* __restrict__ b2,
                            float* __restrict__ out) {
    int b = blockIdx.y, r = blockIdx.x, c = threadIdx.x;
    float av = b2[0], bv = b2[1];
#pragma unroll
    for (int l = 0; l < LAT; l++) {
        float h = hraw[b * LAT + l] + b1[l];
        h = h > 0.0f ? h : 0.0f;
        av += h * w2[l * 2 + 0];
        bv += h * w2[l * 2 + 1];
    }
    const float g   = 0.6065306597126334f;     // exp(-0.5)
    const float inv = 1.0f / (1.0f + 2.0f * g);
    const float* I = img + (size_t)b * XS2;
    float up  = (r > 0)      ? I[(r - 1) * XS + c] : 0.0f;
    float mid =                I[r * XS + c];
    float dn  = (r < XS - 1) ? I[(r + 1) * XS + c] : 0.0f;
    float v = (g * (up + dn) + mid) * inv;
    __shared__ float row[XS + 2];
    row[c + 1] = v;
    if (c == 0) { row[0] = 0.0f; row[XS + 1] = 0.0f; }
    __syncthreads();
    float hh = (g * (row[c] + row[c + 2]) + v) * inv;
    out[(size_t)b * XS2 + (size_t)r * XS + c] = av * hh + bv;
}

extern "C" void kernel_launch(void* const* d_in, const int* in_sizes, int n_in,
                              void* d_out, int out_size, void* d_ws, size_t ws_size,
                              hipStream_t stream) {
    const float* flow   = (const float*)d_in[0];
    const float* x      = (const float*)d_in[1];
    const float* values = (const float*)d_in[2];
    const float* rot    = (const float*)d_in[3];
    const float* shifts = (const float*)d_in[4];
    const float* w1     = (const float*)d_in[5];
    const float* b1     = (const float*)d_in[6];
    const float* w2     = (const float*)d_in[7];
    const float* b2     = (const float*)d_in[8];
    const int*   inds   = (const int*)d_in[9];

    int N = in_sizes[2];          // values: (N,)
    int B = in_sizes[4] / 2;      // shifts: (B,2)
    int TI  = B * N;
    int IPB = (TI + P1 - 1) / P1;
    int NB  = B * NG;

    // workspace layout
    size_t imgElems = (size_t)B * XS2;
    float*    img    = (float*)d_ws;
    float*    hraw   = img + imgElems;                 // 256 floats reserved
    unsigned* totals = (unsigned*)(hraw + 256);        // MAXBINS
    unsigned* base   = totals + MAXBINS;               // MAXBINS
    unsigned* hist   = base + MAXBINS;                 // MAXBINS*P1
    unsigned* offs   = hist + (size_t)MAXBINS * P1;    // MAXBINS*P1
    unsigned* hdrA   = offs + (size_t)MAXBINS * P1;    // TI
    unsigned* fracA  = hdrA + TI;                      // TI
    float*    ampA   = (float*)(fracA + TI);           // TI
    size_t needed = (size_t)((char*)(ampA + TI) - (char*)d_ws);

    bool fastpath = (NB <= MAXBINS) && (ws_size >= needed);

    hipMemsetAsync(d_ws, 0, (imgElems + 256) * sizeof(float), stream);

    if (fastpath) {
        hist_kernel<<<P1, 256, 0, stream>>>(flow, inds, rot, shifts, hist, N, TI, IPB, NB);
        bin_total_kernel<<<NB, 256, 0, stream>>>(hist, totals);
        base_scan_kernel<<<1, MAXBINS, 0, stream>>>(totals, base, NB);
        offs_scan_kernel<<<NB, 256, 0, stream>>>(hist, base, offs);
        place_kernel<<<P1, 256, 0, stream>>>(flow, values, inds, rot, shifts, offs,
                                             hdrA, fracA, ampA, img, N, TI, IPB, NB);
        accum_kernel<<<NB, 256, 0, stream>>>(hdrA, fracA, ampA, base, totals, img);
    } else {
        dim3 g1((N + 255) / 256, B);
        scatter_kernel<<<g1, 256, 0, stream>>>(flow, values, inds, rot, shifts, img, N);
    }

    mlp_partial<<<XS2 / 256, 256, 0, stream>>>(x, w1, hraw, B);

    dim3 g3(XS, B);
    blur_kernel<<<g3, XS, 0, stream>>>(img, hraw, b1, w2, b2, (float*)d_out);
}

// Round 3
// 373.712 us; speedup vs baseline: 3.6335x; 1.0897x over previous
//
#include <hip/hip_runtime.h>

#define XS    256
#define XS2   65536
#define LAT   10
#define BR    8            // rows per bin group
#define NG    (XS / BR)    // 32 groups per image
#define P1    2048         // blocks for hist/place passes
#define MAXBINS 512
#define SPLIT 4            // accum sub-blocks per bin

// ---------------------------------------------------------------------------
// Shared coordinate math — pinned with fmaf so hist and place agree exactly.
// ---------------------------------------------------------------------------
__device__ __forceinline__ void compute_rc(const float* __restrict__ flow,
                                           const int* __restrict__ inds,
                                           const float* __restrict__ rot,
                                           const float* __restrict__ shifts,
                                           int b, int n, int N,
                                           int& r, int& c, float& f0, float& f1) {
    const float* R = rot + b * 9;
    float r00 = R[0], r01 = R[1], r02 = R[2];
    float r10 = R[3], r11 = R[4], r12 = R[5];
    float s0 = shifts[b * 2 + 0], s1 = shifts[b * 2 + 1];
    size_t fo = ((size_t)b * N + n) * 3;
    float fw0 = flow[fo + 0], fw1 = flow[fo + 1], fw2 = flow[fo + 2];
    float v0 = (float)inds[n * 3 + 2] - 128.0f + fw0;
    float v1 = (float)inds[n * 3 + 1] - 128.0f + fw1;
    float v2 = (float)inds[n * 3 + 0] - 128.0f + fw2;
    float p0 = fmaf(v0, r00, fmaf(v1, r01, fmaf(v2, r02, 128.0f - s0)));
    float p1 = fmaf(v0, r10, fmaf(v1, r11, fmaf(v2, r12, 128.0f - s1)));
    float cs0 = p1, cs1 = p0;
    float ff0 = floorf(cs0), ff1 = floorf(cs1);
    r = (int)ff0; c = (int)ff1;
    f0 = cs0 - ff0; f1 = cs1 - ff1;
}

__device__ __forceinline__ void corner_atomic(float* I, int rr, int cc, float a) {
    if (rr >= -XS && rr < XS && cc >= -XS && cc < XS)
        atomicAdd(I + ((rr + XS) & (XS - 1)) * XS + ((cc + XS) & (XS - 1)), a);
}

// fast path iff rows r, r+1 both valid and don't wrap-split.
__device__ __forceinline__ bool is_fast(int r) {
    return (r >= -XS) && (r <= XS - 2) && (r != -1);
}

// ---------------------------------------------------------------------------
// Pass 1: histogram with per-wave sub-histograms (less same-address serial).
// ---------------------------------------------------------------------------
__global__ void hist_kernel(const float* __restrict__ flow,
                            const int* __restrict__ inds,
                            const float* __restrict__ rot,
                            const float* __restrict__ shifts,
                            unsigned* __restrict__ hist,
                            int N, int TI, int IPB, int NB) {
    __shared__ unsigned lh[4 * MAXBINS];
    int t = threadIdx.x, w = t >> 6;
    for (int k = t; k < 4 * MAXBINS; k += 256) lh[k] = 0;
    __syncthreads();
    int s = blockIdx.x * IPB;
    int e = min(s + IPB, TI);
    for (int i = s + t; i < e; i += 256) {
        int b = i / N, n = i - b * N;
        int r, c; float f0, f1;
        compute_rc(flow, inds, rot, shifts, b, n, N, r, c, f0, f1);
        if (is_fast(r)) {
            int wr = (r + XS) & (XS - 1);
            atomicAdd(&lh[w * MAXBINS + b * NG + (wr >> 3)], 1u);
        }
    }
    __syncthreads();
    for (int k = t; k < NB; k += 256)
        hist[(size_t)k * P1 + blockIdx.x] =
            lh[k] + lh[MAXBINS + k] + lh[2 * MAXBINS + k] + lh[3 * MAXBINS + k];
}

// ---------------------------------------------------------------------------
// Pass 2a: per-bin totals.
// ---------------------------------------------------------------------------
__global__ void bin_total_kernel(const unsigned* __restrict__ hist,
                                 unsigned* __restrict__ totals) {
    int bin = blockIdx.x, t = threadIdx.x;
    unsigned s = 0;
    for (int p = t; p < P1; p += 256) s += hist[(size_t)bin * P1 + p];
    __shared__ unsigned red[256];
    red[t] = s; __syncthreads();
    for (int st = 128; st > 0; st >>= 1) {
        if (t < st) red[t] += red[t + st];
        __syncthreads();
    }
    if (t == 0) totals[bin] = red[0];
}

// ---------------------------------------------------------------------------
// Pass 2b: exclusive scan of bin totals (one block).
// ---------------------------------------------------------------------------
__global__ void base_scan_kernel(const unsigned* __restrict__ totals,
                                 unsigned* __restrict__ base, int nb) {
    __shared__ unsigned sh[MAXBINS];
    int t = threadIdx.x;
    unsigned v = (t < nb) ? totals[t] : 0u;
    sh[t] = v; __syncthreads();
    for (int st = 1; st < MAXBINS; st <<= 1) {
        unsigned add = (t >= st) ? sh[t - st] : 0u;
        __syncthreads();
        sh[t] += add;
        __syncthreads();
    }
    if (t < nb) base[t] = sh[t] - v;
}

// ---------------------------------------------------------------------------
// Pass 2c: per-bin exclusive scan over P1 block counts.
// ---------------------------------------------------------------------------
__global__ void offs_scan_kernel(const unsigned* __restrict__ hist,
                                 const unsigned* __restrict__ base,
                                 unsigned* __restrict__ offs) {
    int bin = blockIdx.x, t = threadIdx.x;
    const unsigned* h = hist + (size_t)bin * P1;
    unsigned* o = offs + (size_t)bin * P1;
    unsigned v[P1 / 256]; unsigned s = 0;
#pragma unroll
    for (int k = 0; k < P1 / 256; k++) { v[k] = h[t * (P1 / 256) + k]; s += v[k]; }
    __shared__ unsigned sh[256];
    sh[t] = s; __syncthreads();
    for (int st = 1; st < 256; st <<= 1) {
        unsigned add = (t >= st) ? sh[t - st] : 0u;
        __syncthreads();
        sh[t] += add;
        __syncthreads();
    }
    unsigned run = base[bin] + sh[t] - s;
#pragma unroll
    for (int k = 0; k < P1 / 256; k++) { o[t * (P1 / 256) + k] = run; run += v[k]; }
}

// ---------------------------------------------------------------------------
// Pass 3: place 8-byte records. word: rig[0:2] wc[3:10] cv0[11] cv1[12]
// q0[13:21] q1[22:30] ; high 32 = amp f32 bits. One dwordx2 store per record.
// ---------------------------------------------------------------------------
__global__ void place_kernel(const float* __restrict__ flow,
                             const float* __restrict__ values,
                             const int* __restrict__ inds,
                             const float* __restrict__ rot,
                             const float* __restrict__ shifts,
                             const unsigned* __restrict__ offs,
                             unsigned long long* __restrict__ recs,
                             float* __restrict__ img,
                             int N, int TI, int IPB, int NB) {
    __shared__ unsigned cur[MAXBINS];
    int t = threadIdx.x;
    for (int k = t; k < NB; k += 256) cur[k] = offs[(size_t)k * P1 + blockIdx.x];
    __syncthreads();
    int s = blockIdx.x * IPB;
    int e = min(s + IPB, TI);
    for (int i = s + t; i < e; i += 256) {
        int b = i / N, n = i - b * N;
        int r, c; float f0, f1;
        compute_rc(flow, inds, rot, shifts, b, n, N, r, c, f0, f1);
        float amp = values[n];
        if (is_fast(r)) {
            int wr = (r + XS) & (XS - 1);
            int wc = c & (XS - 1);
            unsigned cv0 = (c >= -XS && c < XS) ? 1u : 0u;
            unsigned cv1 = (c + 1 >= -XS && c + 1 < XS) ? 1u : 0u;
            unsigned q0 = min(511u, (unsigned)(f0 * 512.0f + 0.5f));
            unsigned q1 = min(511u, (unsigned)(f1 * 512.0f + 0.5f));
            unsigned word = (unsigned)(wr & 7) | ((unsigned)wc << 3) |
                            (cv0 << 11) | (cv1 << 12) | (q0 << 13) | (q1 << 22);
            unsigned idx = atomicAdd(&cur[b * NG + (wr >> 3)], 1u);
            recs[idx] = ((unsigned long long)__float_as_uint(amp) << 32) | word;
        } else {
            float a0 = amp * (1.0f - f0) * (1.0f - f1);
            float a1 = amp * f0 * (1.0f - f1);
            float a2 = amp * f0 * f1;
            float a3 = amp * (1.0f - f0) * f1;
            float* I = img + (size_t)b * XS2;
            corner_atomic(I, r,     c,     a0);
            corner_atomic(I, r + 1, c,     a1);
            corner_atomic(I, r + 1, c + 1, a2);
            corner_atomic(I, r,     c + 1, a3);
        }
    }
}

// ---------------------------------------------------------------------------
// Common record unpack + LDS accumulate body.
// ---------------------------------------------------------------------------
__device__ __forceinline__ void accum_record(unsigned long long rec, float* tile) {
    unsigned word = (unsigned)rec;
    float amp = __uint_as_float((unsigned)(rec >> 32));
    int rig = word & 7, wc = (word >> 3) & 255;
    float f0 = (float)((word >> 13) & 511) * (1.0f / 512.0f);
    float f1 = (float)((word >> 22) & 511) * (1.0f / 512.0f);
    int o0 = rig * XS + wc;
    float g0 = 1.0f - f0, g1 = 1.0f - f1;
    if (word & (1u << 11)) {
        atomicAdd(&tile[o0],      amp * g0 * g1);
        atomicAdd(&tile[o0 + XS], amp * f0 * g1);
    }
    if (word & (1u << 12)) {
        int p0 = rig * XS + ((wc + 1) & (XS - 1));
        atomicAdd(&tile[p0],      amp * g0 * f1);
        atomicAdd(&tile[p0 + XS], amp * f0 * f1);
    }
}

// ---------------------------------------------------------------------------
// Pass 4 (full): SPLIT sub-blocks per bin; flush via plain stores to replica
// + apron buffer (exclusive ownership -> no atomics).
// ---------------------------------------------------------------------------
__global__ void accum_split_kernel(const unsigned long long* __restrict__ recs,
                                   const unsigned* __restrict__ base,
                                   const unsigned* __restrict__ totals,
                                   float* __restrict__ reps,
                                   float* __restrict__ aprons, int B) {
    int bin = blockIdx.x / SPLIT, sp = blockIdx.x - bin * SPLIT;
    int b = bin >> 5, g = bin & 31;
    __shared__ float tile[(BR + 1) * XS];
    int t = threadIdx.x;
    for (int k = t; k < (BR + 1) * XS; k += 256) tile[k] = 0.0f;
    __syncthreads();
    unsigned bs = base[bin], cnt = totals[bin];
    unsigned lo = bs + (unsigned)(((unsigned long long)cnt * sp) / SPLIT);
    unsigned hi = bs + (unsigned)(((unsigned long long)cnt * (sp + 1)) / SPLIT);
    for (unsigned i = lo + t; i < hi; i += 256) accum_record(recs[i], tile);
    __syncthreads();
    float* rep = reps + ((size_t)sp * B + b) * XS2;
    for (int k = t; k < (BR + 1) * XS; k += 256) {
        int row = k >> 8, col = k & 255;
        if (row < BR) rep[(g * BR + row) * XS + col] = tile[k];
        else          aprons[((size_t)bin * SPLIT + sp) * XS + col] = tile[k];
    }
}

// ---------------------------------------------------------------------------
// Pass 4 (fallback): unsplit, atomic flush into img (round-2 behavior).
// ---------------------------------------------------------------------------
__global__ void accum_kernel(const unsigned long long* __restrict__ recs,
                             const unsigned* __restrict__ base,
                             const unsigned* __restrict__ totals,
                             float* __restrict__ img) {
    int bin = blockIdx.x;
    int b = bin >> 5, g = bin & 31;
    __shared__ float tile[(BR + 1) * XS];
    int t = threadIdx.x;
    for (int k = t; k < (BR + 1) * XS; k += 256) tile[k] = 0.0f;
    __syncthreads();
    unsigned s = base[bin], cnt = totals[bin];
    for (unsigned i = s + t; i < s + cnt; i += 256) accum_record(recs[i], tile);
    __syncthreads();
    float* I = img + (size_t)b * XS2;
    for (int k = t; k < (BR + 1) * XS; k += 256) {
        float v = tile[k];
        if (v != 0.0f) {
            int rr = (g * BR + (k >> 8)) & (XS - 1);
            atomicAdd(&I[rr * XS + (k & 255)], v);
        }
    }
}

// ---------------------------------------------------------------------------
// Pass 5 (full path): img += sum of replicas (+ aprons at r = 8k).
// ---------------------------------------------------------------------------
__global__ void combine_kernel(float* __restrict__ img,
                               const float* __restrict__ reps,
                               const float* __restrict__ aprons, int B) {
    int b = blockIdx.y, r = blockIdx.x, c = threadIdx.x;
    size_t off = (size_t)b * XS2 + r * XS + c;
    float v = img[off];
#pragma unroll
    for (int sp = 0; sp < SPLIT; sp++)
        v += reps[((size_t)sp * B + b) * XS2 + r * XS + c];
    if (r >= BR && (r & (BR - 1)) == 0) {
        int g = (r >> 3) - 1;
        int bin = b * NG + g;
#pragma unroll
        for (int sp = 0; sp < SPLIT; sp++)
            v += aprons[((size_t)bin * SPLIT + sp) * XS + c];
    }
    img[off] = v;
}

// ---------------------------------------------------------------------------
// Fallback direct-scatter (tiny ws).
// ---------------------------------------------------------------------------
__global__ void scatter_kernel(const float* __restrict__ flow,
                               const float* __restrict__ values,
                               const int* __restrict__ inds,
                               const float* __restrict__ rot,
                               const float* __restrict__ shifts,
                               float* __restrict__ img, int N) {
    int b = blockIdx.y;
    int n = blockIdx.x * blockDim.x + threadIdx.x;
    if (n >= N) return;
    int r, c; float f0, f1;
    compute_rc(flow, inds, rot, shifts, b, n, N, r, c, f0, f1);
    float amp = values[n];
    float a0 = amp * (1.0f - f0) * (1.0f - f1);
    float a1 = amp * f0 * (1.0f - f1);
    float a2 = amp * f0 * f1;
    float a3 = amp * (1.0f - f0) * f1;
    float* I = img + (size_t)b * XS2;
    corner_atomic(I, r,     c,     a0);
    corner_atomic(I, r + 1, c,     a1);
    corner_atomic(I, r + 1, c + 1, a2);
    corner_atomic(I, r,     c + 1, a3);
}

// ---------------------------------------------------------------------------
// MLP split-K partials.
// ---------------------------------------------------------------------------
__global__ void mlp_partial(const float* __restrict__ x,
                            const float* __restrict__ w1,
                            float* __restrict__ hraw, int B) {
    int base = blockIdx.x * 256;
    int t = threadIdx.x;
    if (t >= B * LAT) return;
    int b = t / LAT, l = t - b * LAT;
    const float* xb = x + (size_t)b * XS2 + base;
    const float* w  = w1 + (size_t)base * LAT + l;
    float acc = 0.0f;
#pragma unroll 8
    for (int e = 0; e < 256; e++) acc += xb[e] * w[e * LAT];
    atomicAdd(&hraw[b * LAT + l], acc);
}

// ---------------------------------------------------------------------------
// Separable 3x3 blur + per-batch affine.
// ---------------------------------------------------------------------------
__global__ void blur_kernel(const float* __restrict__ img,
                            const float* __restrict__ hraw,
                            const float* __restrict__ b1,
                            const float* __restrict__ w2,
                            const float* __restrict__ b2,
                            float* __restrict__ out) {
    int b = blockIdx.y, r = blockIdx.x, c = threadIdx.x;
    float av = b2[0], bv = b2[1];
#pragma unroll
    for (int l = 0; l < LAT; l++) {
        float h = hraw[b * LAT + l] + b1[l];
        h = h > 0.0f ? h : 0.0f;
        av += h * w2[l * 2 + 0];
        bv += h * w2[l * 2 + 1];
    }
    const float g   = 0.6065306597126334f;
    const float inv = 1.0f / (1.0f + 2.0f * g);
    const float* I = img + (size_t)b * XS2;
    float up  = (r > 0)      ? I[(r - 1) * XS + c] : 0.0f;
    float mid =                I[r * XS + c];
    float dn  = (r < XS - 1) ? I[(r + 1) * XS + c] : 0.0f;
    float v = (g * (up + dn) + mid) * inv;
    __shared__ float row[XS + 2];
    row[c + 1] = v;
    if (c == 0) { row[0] = 0.0f; row[XS + 1] = 0.0f; }
    __syncthreads();
    float hh = (g * (row[c] + row[c + 2]) + v) * inv;
    out[(size_t)b * XS2 + (size_t)r * XS + c] = av * hh + bv;
}

extern "C" void kernel_launch(void* const* d_in, const int* in_sizes, int n_in,
                              void* d_out, int out_size, void* d_ws, size_t ws_size,
                              hipStream_t stream) {
    const float* flow   = (const float*)d_in[0];
    const float* x      = (const float*)d_in[1];
    const float* values = (const float*)d_in[2];
    const float* rot    = (const float*)d_in[3];
    const float* shifts = (const float*)d_in[4];
    const float* w1     = (const float*)d_in[5];
    const float* b1     = (const float*)d_in[6];
    const float* w2     = (const float*)d_in[7];
    const float* b2     = (const float*)d_in[8];
    const int*   inds   = (const int*)d_in[9];

    int N = in_sizes[2];
    int B = in_sizes[4] / 2;
    int TI  = B * N;
    int IPB = (TI + P1 - 1) / P1;
    int NB  = B * NG;

    // workspace layout (8B-aligned: all chunks are multiples of 8B given
    // B*XS2, MAXBINS, P1 sizes)
    size_t imgElems = (size_t)B * XS2;
    float*    img    = (float*)d_ws;
    float*    hraw   = img + imgElems;                 // 256 floats reserved
    unsigned* totals = (unsigned*)(hraw + 256);        // MAXBINS
    unsigned* base   = totals + MAXBINS;               // MAXBINS
    unsigned* hist   = base + MAXBINS;                 // MAXBINS*P1
    unsigned* offs   = hist + (size_t)MAXBINS * P1;    // MAXBINS*P1
    unsigned long long* recs = (unsigned long long*)(offs + (size_t)MAXBINS * P1); // TI
    float*    reps   = (float*)(recs + TI);            // SPLIT*B*XS2
    float*    aprons = reps + (size_t)SPLIT * imgElems;// NB*SPLIT*XS
    size_t needed_full = (size_t)((char*)(aprons + (size_t)NB * SPLIT * XS) - (char*)d_ws);
    size_t needed_base = (size_t)((char*)reps - (char*)d_ws);

    bool sortpath = (NB <= MAXBINS) && (ws_size >= needed_base);
    bool fullpath = sortpath && (ws_size >= needed_full);

    hipMemsetAsync(d_ws, 0, (imgElems + 256) * sizeof(float), stream);

    if (sortpath) {
        hist_kernel<<<P1, 256, 0, stream>>>(flow, inds, rot, shifts, hist, N, TI, IPB, NB);
        bin_total_kernel<<<NB, 256, 0, stream>>>(hist, totals);
        base_scan_kernel<<<1, MAXBINS, 0, stream>>>(totals, base, NB);
        offs_scan_kernel<<<NB, 256, 0, stream>>>(hist, base, offs);
        place_kernel<<<P1, 256, 0, stream>>>(flow, values, inds, rot, shifts, offs,
                                             recs, img, N, TI, IPB, NB);
        if (fullpath) {
            accum_split_kernel<<<NB * SPLIT, 256, 0, stream>>>(recs, base, totals,
                                                               reps, aprons, B);
            dim3 gc(XS, B);
            combine_kernel<<<gc, 256, 0, stream>>>(img, reps, aprons, B);
        } else {
            accum_kernel<<<NB, 256, 0, stream>>>(recs, base, totals, img);
        }
    } else {
        dim3 g1((N + 255) / 256, B);
        scatter_kernel<<<g1, 256, 0, stream>>>(flow, values, inds, rot, shifts, img, N);
    }

    mlp_partial<<<XS2 / 256, 256, 0, stream>>>(x, w1, hraw, B);

    dim3 g3(XS, B);
    blur_kernel<<<g3, XS, 0, stream>>>(img, hraw, b1, w2, b2, (float*)d_out);
}

// Round 4
// 373.155 us; speedup vs baseline: 3.6389x; 1.0015x over previous
//
#include <hip/hip_runtime.h>

#define XS    256
#define XS2   65536
#define LAT   10
#define BR    8            // rows per bin group
#define NG    (XS / BR)    // 32 groups per image
#define P1    2048         // blocks for hist/place passes
#define MAXBINS 512
#define SPLIT 4            // accum sub-blocks per bin

// Native f32 atomic add (ds_add_f32 / global_atomic_add_f32).
// Plain atomicAdd(float*) lowers to a CAS loop without -munsafe-fp-atomics,
// which was the ~3.3 cyc/lane wall in rounds 1-3.
__device__ __forceinline__ void fadd_atomic(float* p, float v) {
    unsafeAtomicAdd(p, v);
}

// ---------------------------------------------------------------------------
// Shared coordinate math — pinned with fmaf so hist and place agree exactly.
// ---------------------------------------------------------------------------
__device__ __forceinline__ void compute_rc(const float* __restrict__ flow,
                                           const int* __restrict__ inds,
                                           const float* __restrict__ rot,
                                           const float* __restrict__ shifts,
                                           int b, int n, int N,
                                           int& r, int& c, float& f0, float& f1) {
    const float* R = rot + b * 9;
    float r00 = R[0], r01 = R[1], r02 = R[2];
    float r10 = R[3], r11 = R[4], r12 = R[5];
    float s0 = shifts[b * 2 + 0], s1 = shifts[b * 2 + 1];
    size_t fo = ((size_t)b * N + n) * 3;
    float fw0 = flow[fo + 0], fw1 = flow[fo + 1], fw2 = flow[fo + 2];
    float v0 = (float)inds[n * 3 + 2] - 128.0f + fw0;
    float v1 = (float)inds[n * 3 + 1] - 128.0f + fw1;
    float v2 = (float)inds[n * 3 + 0] - 128.0f + fw2;
    float p0 = fmaf(v0, r00, fmaf(v1, r01, fmaf(v2, r02, 128.0f - s0)));
    float p1 = fmaf(v0, r10, fmaf(v1, r11, fmaf(v2, r12, 128.0f - s1)));
    float cs0 = p1, cs1 = p0;
    float ff0 = floorf(cs0), ff1 = floorf(cs1);
    r = (int)ff0; c = (int)ff1;
    f0 = cs0 - ff0; f1 = cs1 - ff1;
}

__device__ __forceinline__ void corner_atomic(float* I, int rr, int cc, float a) {
    if (rr >= -XS && rr < XS && cc >= -XS && cc < XS)
        fadd_atomic(I + ((rr + XS) & (XS - 1)) * XS + ((cc + XS) & (XS - 1)), a);
}

// fast path iff rows r, r+1 both valid and don't wrap-split.
__device__ __forceinline__ bool is_fast(int r) {
    return (r >= -XS) && (r <= XS - 2) && (r != -1);
}

// ---------------------------------------------------------------------------
// Pass 1: histogram with per-wave sub-histograms.
// ---------------------------------------------------------------------------
__global__ void hist_kernel(const float* __restrict__ flow,
                            const int* __restrict__ inds,
                            const float* __restrict__ rot,
                            const float* __restrict__ shifts,
                            unsigned* __restrict__ hist,
                            int N, int TI, int IPB, int NB) {
    __shared__ unsigned lh[4 * MAXBINS];
    int t = threadIdx.x, w = t >> 6;
    for (int k = t; k < 4 * MAXBINS; k += 256) lh[k] = 0;
    __syncthreads();
    int s = blockIdx.x * IPB;
    int e = min(s + IPB, TI);
    for (int i = s + t; i < e; i += 256) {
        int b = i / N, n = i - b * N;
        int r, c; float f0, f1;
        compute_rc(flow, inds, rot, shifts, b, n, N, r, c, f0, f1);
        if (is_fast(r)) {
            int wr = (r + XS) & (XS - 1);
            atomicAdd(&lh[w * MAXBINS + b * NG + (wr >> 3)], 1u);
        }
    }
    __syncthreads();
    for (int k = t; k < NB; k += 256)
        hist[(size_t)k * P1 + blockIdx.x] =
            lh[k] + lh[MAXBINS + k] + lh[2 * MAXBINS + k] + lh[3 * MAXBINS + k];
}

// ---------------------------------------------------------------------------
// Pass 2a: per-bin totals.
// ---------------------------------------------------------------------------
__global__ void bin_total_kernel(const unsigned* __restrict__ hist,
                                 unsigned* __restrict__ totals) {
    int bin = blockIdx.x, t = threadIdx.x;
    unsigned s = 0;
    for (int p = t; p < P1; p += 256) s += hist[(size_t)bin * P1 + p];
    __shared__ unsigned red[256];
    red[t] = s; __syncthreads();
    for (int st = 128; st > 0; st >>= 1) {
        if (t < st) red[t] += red[t + st];
        __syncthreads();
    }
    if (t == 0) totals[bin] = red[0];
}

// ---------------------------------------------------------------------------
// Pass 2b: exclusive scan of bin totals (one block).
// ---------------------------------------------------------------------------
__global__ void base_scan_kernel(const unsigned* __restrict__ totals,
                                 unsigned* __restrict__ base, int nb) {
    __shared__ unsigned sh[MAXBINS];
    int t = threadIdx.x;
    unsigned v = (t < nb) ? totals[t] : 0u;
    sh[t] = v; __syncthreads();
    for (int st = 1; st < MAXBINS; st <<= 1) {
        unsigned add = (t >= st) ? sh[t - st] : 0u;
        __syncthreads();
        sh[t] += add;
        __syncthreads();
    }
    if (t < nb) base[t] = sh[t] - v;
}

// ---------------------------------------------------------------------------
// Pass 2c: per-bin exclusive scan over P1 block counts.
// ---------------------------------------------------------------------------
__global__ void offs_scan_kernel(const unsigned* __restrict__ hist,
                                 const unsigned* __restrict__ base,
                                 unsigned* __restrict__ offs) {
    int bin = blockIdx.x, t = threadIdx.x;
    const unsigned* h = hist + (size_t)bin * P1;
    unsigned* o = offs + (size_t)bin * P1;
    unsigned v[P1 / 256]; unsigned s = 0;
#pragma unroll
    for (int k = 0; k < P1 / 256; k++) { v[k] = h[t * (P1 / 256) + k]; s += v[k]; }
    __shared__ unsigned sh[256];
    sh[t] = s; __syncthreads();
    for (int st = 1; st < 256; st <<= 1) {
        unsigned add = (t >= st) ? sh[t - st] : 0u;
        __syncthreads();
        sh[t] += add;
        __syncthreads();
    }
    unsigned run = base[bin] + sh[t] - s;
#pragma unroll
    for (int k = 0; k < P1 / 256; k++) { o[t * (P1 / 256) + k] = run; run += v[k]; }
}

// ---------------------------------------------------------------------------
// Pass 3: place 8-byte records. word: rig[0:2] wc[3:10] cv0[11] cv1[12]
// q0[13:21] q1[22:30] ; high 32 = amp f32 bits.
// ---------------------------------------------------------------------------
__global__ void place_kernel(const float* __restrict__ flow,
                             const float* __restrict__ values,
                             const int* __restrict__ inds,
                             const float* __restrict__ rot,
                             const float* __restrict__ shifts,
                             const unsigned* __restrict__ offs,
                             unsigned long long* __restrict__ recs,
                             float* __restrict__ img,
                             int N, int TI, int IPB, int NB) {
    __shared__ unsigned cur[MAXBINS];
    int t = threadIdx.x;
    for (int k = t; k < NB; k += 256) cur[k] = offs[(size_t)k * P1 + blockIdx.x];
    __syncthreads();
    int s = blockIdx.x * IPB;
    int e = min(s + IPB, TI);
    for (int i = s + t; i < e; i += 256) {
        int b = i / N, n = i - b * N;
        int r, c; float f0, f1;
        compute_rc(flow, inds, rot, shifts, b, n, N, r, c, f0, f1);
        float amp = values[n];
        if (is_fast(r)) {
            int wr = (r + XS) & (XS - 1);
            int wc = c & (XS - 1);
            unsigned cv0 = (c >= -XS && c < XS) ? 1u : 0u;
            unsigned cv1 = (c + 1 >= -XS && c + 1 < XS) ? 1u : 0u;
            unsigned q0 = min(511u, (unsigned)(f0 * 512.0f + 0.5f));
            unsigned q1 = min(511u, (unsigned)(f1 * 512.0f + 0.5f));
            unsigned word = (unsigned)(wr & 7) | ((unsigned)wc << 3) |
                            (cv0 << 11) | (cv1 << 12) | (q0 << 13) | (q1 << 22);
            unsigned idx = atomicAdd(&cur[b * NG + (wr >> 3)], 1u);
            recs[idx] = ((unsigned long long)__float_as_uint(amp) << 32) | word;
        } else {
            float a0 = amp * (1.0f - f0) * (1.0f - f1);
            float a1 = amp * f0 * (1.0f - f1);
            float a2 = amp * f0 * f1;
            float a3 = amp * (1.0f - f0) * f1;
            float* I = img + (size_t)b * XS2;
            corner_atomic(I, r,     c,     a0);
            corner_atomic(I, r + 1, c,     a1);
            corner_atomic(I, r + 1, c + 1, a2);
            corner_atomic(I, r,     c + 1, a3);
        }
    }
}

// ---------------------------------------------------------------------------
// Common record unpack + LDS accumulate body (native ds_add_f32).
// ---------------------------------------------------------------------------
__device__ __forceinline__ void accum_record(unsigned long long rec, float* tile) {
    unsigned word = (unsigned)rec;
    float amp = __uint_as_float((unsigned)(rec >> 32));
    int rig = word & 7, wc = (word >> 3) & 255;
    float f0 = (float)((word >> 13) & 511) * (1.0f / 512.0f);
    float f1 = (float)((word >> 22) & 511) * (1.0f / 512.0f);
    int o0 = rig * XS + wc;
    float g0 = 1.0f - f0, g1 = 1.0f - f1;
    if (word & (1u << 11)) {
        fadd_atomic(&tile[o0],      amp * g0 * g1);
        fadd_atomic(&tile[o0 + XS], amp * f0 * g1);
    }
    if (word & (1u << 12)) {
        int p0 = rig * XS + ((wc + 1) & (XS - 1));
        fadd_atomic(&tile[p0],      amp * g0 * f1);
        fadd_atomic(&tile[p0 + XS], amp * f0 * f1);
    }
}

// ---------------------------------------------------------------------------
// Pass 4 (full): SPLIT sub-blocks per bin; flush via plain stores.
// ---------------------------------------------------------------------------
__global__ void accum_split_kernel(const unsigned long long* __restrict__ recs,
                                   const unsigned* __restrict__ base,
                                   const unsigned* __restrict__ totals,
                                   float* __restrict__ reps,
                                   float* __restrict__ aprons, int B) {
    int bin = blockIdx.x / SPLIT, sp = blockIdx.x - bin * SPLIT;
    int b = bin >> 5, g = bin & 31;
    __shared__ float tile[(BR + 1) * XS];
    int t = threadIdx.x;
    for (int k = t; k < (BR + 1) * XS; k += 256) tile[k] = 0.0f;
    __syncthreads();
    unsigned bs = base[bin], cnt = totals[bin];
    unsigned lo = bs + (unsigned)(((unsigned long long)cnt * sp) / SPLIT);
    unsigned hi = bs + (unsigned)(((unsigned long long)cnt * (sp + 1)) / SPLIT);
    for (unsigned i = lo + t; i < hi; i += 256) accum_record(recs[i], tile);
    __syncthreads();
    float* rep = reps + ((size_t)sp * B + b) * XS2;
    for (int k = t; k < (BR + 1) * XS; k += 256) {
        int row = k >> 8, col = k & 255;
        if (row < BR) rep[(g * BR + row) * XS + col] = tile[k];
        else          aprons[((size_t)bin * SPLIT + sp) * XS + col] = tile[k];
    }
}

// ---------------------------------------------------------------------------
// Pass 4 (fallback): unsplit, atomic flush into img.
// ---------------------------------------------------------------------------
__global__ void accum_kernel(const unsigned long long* __restrict__ recs,
                             const unsigned* __restrict__ base,
                             const unsigned* __restrict__ totals,
                             float* __restrict__ img) {
    int bin = blockIdx.x;
    int b = bin >> 5, g = bin & 31;
    __shared__ float tile[(BR + 1) * XS];
    int t = threadIdx.x;
    for (int k = t; k < (BR + 1) * XS; k += 256) tile[k] = 0.0f;
    __syncthreads();
    unsigned s = base[bin], cnt = totals[bin];
    for (unsigned i = s + t; i < s + cnt; i += 256) accum_record(recs[i], tile);
    __syncthreads();
    float* I = img + (size_t)b * XS2;
    for (int k = t; k < (BR + 1) * XS; k += 256) {
        float v = tile[k];
        if (v != 0.0f) {
            int rr = (g * BR + (k >> 8)) & (XS - 1);
            fadd_atomic(&I[rr * XS + (k & 255)], v);
        }
    }
}

// ---------------------------------------------------------------------------
// Pass 5 (full path): img += sum of replicas (+ aprons at r = 8k).
// ---------------------------------------------------------------------------
__global__ void combine_kernel(float* __restrict__ img,
                               const float* __restrict__ reps,
                               const float* __restrict__ aprons, int B) {
    int b = blockIdx.y, r = blockIdx.x, c = threadIdx.x;
    size_t off = (size_t)b * XS2 + r * XS + c;
    float v = img[off];
#pragma unroll
    for (int sp = 0; sp < SPLIT; sp++)
        v += reps[((size_t)sp * B + b) * XS2 + r * XS + c];
    if (r >= BR && (r & (BR - 1)) == 0) {
        int g = (r >> 3) - 1;
        int bin = b * NG + g;
#pragma unroll
        for (int sp = 0; sp < SPLIT; sp++)
            v += aprons[((size_t)bin * SPLIT + sp) * XS + c];
    }
    img[off] = v;
}

// ---------------------------------------------------------------------------
// Fallback direct-scatter (tiny ws).
// ---------------------------------------------------------------------------
__global__ void scatter_kernel(const float* __restrict__ flow,
                               const float* __restrict__ values,
                               const int* __restrict__ inds,
                               const float* __restrict__ rot,
                               const float* __restrict__ shifts,
                               float* __restrict__ img, int N) {
    int b = blockIdx.y;
    int n = blockIdx.x * blockDim.x + threadIdx.x;
    if (n >= N) return;
    int r, c; float f0, f1;
    compute_rc(flow, inds, rot, shifts, b, n, N, r, c, f0, f1);
    float amp = values[n];
    float a0 = amp * (1.0f - f0) * (1.0f - f1);
    float a1 = amp * f0 * (1.0f - f1);
    float a2 = amp * f0 * f1;
    float a3 = amp * (1.0f - f0) * f1;
    float* I = img + (size_t)b * XS2;
    corner_atomic(I, r,     c,     a0);
    corner_atomic(I, r + 1, c,     a1);
    corner_atomic(I, r + 1, c + 1, a2);
    corner_atomic(I, r,     c + 1, a3);
}

// ---------------------------------------------------------------------------
// MLP split-K partials.
// ---------------------------------------------------------------------------
__global__ void mlp_partial(const float* __restrict__ x,
                            const float* __restrict__ w1,
                            float* __restrict__ hraw, int B) {
    int base = blockIdx.x * 256;
    int t = threadIdx.x;
    if (t >= B * LAT) return;
    int b = t / LAT, l = t - b * LAT;
    const float* xb = x + (size_t)b * XS2 + base;
    const float* w  = w1 + (size_t)base * LAT + l;
    float acc = 0.0f;
#pragma unroll 8
    for (int e = 0; e < 256; e++) acc += xb[e] * w[e * LAT];
    fadd_atomic(&hraw[b * LAT + l], acc);
}

// ---------------------------------------------------------------------------
// Separable 3x3 blur + per-batch affine.
// ---------------------------------------------------------------------------
__global__ void blur_kernel(const float* __restrict__ img,
                            const float* __restrict__ hraw,
                            const float* __restrict__ b1,
                            const float* __restrict__ w2,
                            const float* __restrict__ b2,
                            float* __restrict__ out) {
    int b = blockIdx.y, r = blockIdx.x, c = threadIdx.x;
    float av = b2[0], bv = b2[1];
#pragma unroll
    for (int l = 0; l < LAT; l++) {
        float h = hraw[b * LAT + l] + b1[l];
        h = h > 0.0f ? h : 0.0f;
        av += h * w2[l * 2 + 0];
        bv += h * w2[l * 2 + 1];
    }
    const float g   = 0.6065306597126334f;
    const float inv = 1.0f / (1.0f + 2.0f * g);
    const float* I = img + (size_t)b * XS2;
    float up  = (r > 0)      ? I[(r - 1) * XS + c] : 0.0f;
    float mid =                I[r * XS + c];
    float dn  = (r < XS - 1) ? I[(r + 1) * XS + c] : 0.0f;
    float v = (g * (up + dn) + mid) * inv;
    __shared__ float row[XS + 2];
    row[c + 1] = v;
    if (c == 0) { row[0] = 0.0f; row[XS + 1] = 0.0f; }
    __syncthreads();
    float hh = (g * (row[c] + row[c + 2]) + v) * inv;
    out[(size_t)b * XS2 + (size_t)r * XS + c] = av * hh + bv;
}

extern "C" void kernel_launch(void* const* d_in, const int* in_sizes, int n_in,
                              void* d_out, int out_size, void* d_ws, size_t ws_size,
                              hipStream_t stream) {
    const float* flow   = (const float*)d_in[0];
    const float* x      = (const float*)d_in[1];
    const float* values = (const float*)d_in[2];
    const float* rot    = (const float*)d_in[3];
    const float* shifts = (const float*)d_in[4];
    const float* w1     = (const float*)d_in[5];
    const float* b1     = (const float*)d_in[6];
    const float* w2     = (const float*)d_in[7];
    const float* b2     = (const float*)d_in[8];
    const int*   inds   = (const int*)d_in[9];

    int N = in_sizes[2];
    int B = in_sizes[4] / 2;
    int TI  = B * N;
    int IPB = (TI + P1 - 1) / P1;
    int NB  = B * NG;

    size_t imgElems = (size_t)B * XS2;
    float*    img    = (float*)d_ws;
    float*    hraw   = img + imgElems;                 // 256 floats reserved
    unsigned* totals = (unsigned*)(hraw + 256);        // MAXBINS
    unsigned* base   = totals + MAXBINS;               // MAXBINS
    unsigned* hist   = base + MAXBINS;                 // MAXBINS*P1
    unsigned* offs   = hist + (size_t)MAXBINS * P1;    // MAXBINS*P1
    unsigned long long* recs = (unsigned long long*)(offs + (size_t)MAXBINS * P1); // TI
    float*    reps   = (float*)(recs + TI);            // SPLIT*B*XS2
    float*    aprons = reps + (size_t)SPLIT * imgElems;// NB*SPLIT*XS
    size_t needed_full = (size_t)((char*)(aprons + (size_t)NB * SPLIT * XS) - (char*)d_ws);
    size_t needed_base = (size_t)((char*)reps - (char*)d_ws);

    bool sortpath = (NB <= MAXBINS) && (ws_size >= needed_base);
    bool fullpath = sortpath && (ws_size >= needed_full);

    hipMemsetAsync(d_ws, 0, (imgElems + 256) * sizeof(float), stream);

    if (sortpath) {
        hist_kernel<<<P1, 256, 0, stream>>>(flow, inds, rot, shifts, hist, N, TI, IPB, NB);
        bin_total_kernel<<<NB, 256, 0, stream>>>(hist, totals);
        base_scan_kernel<<<1, MAXBINS, 0, stream>>>(totals, base, NB);
        offs_scan_kernel<<<NB, 256, 0, stream>>>(hist, base, offs);
        place_kernel<<<P1, 256, 0, stream>>>(flow, values, inds, rot, shifts, offs,
                                             recs, img, N, TI, IPB, NB);
        if (fullpath) {
            accum_split_kernel<<<NB * SPLIT, 256, 0, stream>>>(recs, base, totals,
                                                               reps, aprons, B);
            dim3 gc(XS, B);
            combine_kernel<<<gc, 256, 0, stream>>>(img, reps, aprons, B);
        } else {
            accum_kernel<<<NB, 256, 0, stream>>>(recs, base, totals, img);
        }
    } else {
        dim3 g1((N + 255) / 256, B);
        scatter_kernel<<<g1, 256, 0, stream>>>(flow, values, inds, rot, shifts, img, N);
    }

    mlp_partial<<<XS2 / 256, 256, 0, stream>>>(x, w1, hraw, B);

    dim3 g3(XS, B);
    blur_kernel<<<g3, XS, 0, stream>>>(img, hraw, b1, w2, b2, (float*)d_out);
}